// Round 1
// baseline (554.450 us; speedup 1.0000x reference)
//
#include <hip/hip_runtime.h>

// Problem constants (B=8, A=3, H=200, W=304)
#define HWSZ 60800      // H*W
#define NA 3
#define NTOT 182400     // A*H*W
#define KSEL 2000
#define BUFCAP 2048
#define NBATCH 8
#define LOG_MAX_F 4.135166556742356f   // log(1000/16) rounded to fp32

// ---- workspace layout (bytes) ----
// buf   : 8 * 2048 * 8  = 131072   @ 0
// cnt   : 8 * 4                    @ 131072
// boxes : 8 * 2000 * 16 = 256000   @ 132096 (16B aligned)
// valid : 8 * 2000 * 4  = 64000    @ 388096
// sup   : 8 * 2000 * 32 * 8 = 4096000 @ 452096 (8B aligned)
#define OFF_BUF   0
#define OFF_CNT   131072
#define OFF_BOX   132096
#define OFF_VALID 388096
#define OFF_SUP   452096

__device__ __forceinline__ unsigned int xform(float f) {
    unsigned int b = __float_as_uint(f);
    // monotonic map: larger float -> larger uint
    return b ^ ((unsigned int)((int)b >> 31) | 0x80000000u);
}

// ---------------- Kernel 1: per-batch radix select + gather ----------------
__global__ __launch_bounds__(1024) void k_select(const float* __restrict__ cls,
                                                 unsigned long long* __restrict__ buf,
                                                 unsigned int* __restrict__ cnt_out) {
    int b = blockIdx.x;
    int tid = threadIdx.x;
    __shared__ unsigned int hist[256];
    __shared__ unsigned int sh_prefix, sh_krem, sh_cnt;
    const float* base = cls + (size_t)b * NA * HWSZ;
    if (tid == 0) { sh_prefix = 0u; sh_krem = KSEL; }

    for (int round = 0; round < 4; ++round) {
        if (tid < 256) hist[tid] = 0u;
        __syncthreads();
        unsigned int prefix = sh_prefix;
        int shift = 24 - 8 * round;
        unsigned int mask = round ? (0xFFFFFFFFu << (shift + 8)) : 0u;
        for (int a = 0; a < NA; ++a) {
            const float* p = base + a * HWSZ;
            for (int hw = tid; hw < HWSZ; hw += 1024) {
                unsigned int u = xform(p[hw]);
                if ((u & mask) == prefix) atomicAdd(&hist[(u >> shift) & 255u], 1u);
            }
        }
        __syncthreads();
        if (tid == 0) {
            unsigned int krem = sh_krem, cum = 0u;
            for (int bin = 255; bin >= 0; --bin) {
                unsigned int c = hist[bin];
                if (cum + c >= krem) {
                    sh_prefix = prefix | ((unsigned int)bin << shift);
                    sh_krem = krem - cum;
                    break;
                }
                cum += c;
            }
        }
        __syncthreads();
    }

    unsigned int Ts = sh_prefix;   // exact k-th largest 32-bit score key
    if (tid == 0) sh_cnt = 0u;
    __syncthreads();
    for (int a = 0; a < NA; ++a) {
        const float* p = base + a * HWSZ;
        for (int hw = tid; hw < HWSZ; hw += 1024) {
            unsigned int u = xform(p[hw]);
            if (u >= Ts) {
                unsigned int pos = atomicAdd(&sh_cnt, 1u);
                if (pos < BUFCAP) {
                    unsigned int n = (unsigned int)(hw * NA + a);
                    buf[(size_t)b * BUFCAP + pos] =
                        ((unsigned long long)u << 32) | (unsigned long long)(~n);
                }
            }
        }
    }
    __syncthreads();
    if (tid == 0) cnt_out[b] = (sh_cnt < BUFCAP) ? sh_cnt : BUFCAP;
}

// -------- Kernel 2: per-batch bitonic sort (desc) + box decode --------
__global__ __launch_bounds__(1024) void k_sort_decode(
        const unsigned long long* __restrict__ buf,
        const unsigned int* __restrict__ cnt_in,
        const float* __restrict__ regs,
        const float* __restrict__ anchors,
        const int* __restrict__ img_h,
        const int* __restrict__ img_w,
        float* __restrict__ out_scores,
        float4* __restrict__ boxes_ws,
        unsigned int* __restrict__ valid_ws) {
    int b = blockIdx.x;
    int tid = threadIdx.x;
    __shared__ unsigned long long arr[BUFCAP];
    unsigned int cnt = cnt_in[b];
    if (cnt > BUFCAP) cnt = BUFCAP;
    for (int i = tid; i < BUFCAP; i += 1024)
        arr[i] = (i < (int)cnt) ? buf[(size_t)b * BUFCAP + i] : 0ULL;
    __syncthreads();

    // bitonic sort, descending by packed key
    for (int k = 2; k <= BUFCAP; k <<= 1) {
        for (int j = k >> 1; j > 0; j >>= 1) {
            for (int i = tid; i < BUFCAP; i += 1024) {
                int ixj = i ^ j;
                if (ixj > i) {
                    unsigned long long x = arr[i], y = arr[ixj];
                    bool up = (i & k) == 0;
                    if (up ? (x < y) : (x > y)) { arr[i] = y; arr[ixj] = x; }
                }
            }
            __syncthreads();
        }
    }

    // robust scalar read (int expected; tolerate float-encoded)
    int hv = img_h[0];
    int wv = img_w[0];
    float himg = (hv > 0 && hv < 100000) ? (float)hv : __int_as_float(hv);
    float wimg = (wv > 0 && wv < 100000) ? (float)wv : __int_as_float(wv);

    for (int r = tid; r < KSEL; r += 1024) {
        unsigned long long packed = arr[r];
        size_t o = (size_t)b * KSEL + r;
        if (packed == 0ULL) {   // defensive — should not happen
            out_scores[o] = 0.f;
            boxes_ws[o] = make_float4(0.f, 0.f, 0.f, 0.f);
            valid_ws[o] = 0u;
            continue;
        }
        unsigned int u = (unsigned int)(packed >> 32);
        unsigned int n = ~((unsigned int)packed);
        unsigned int bits = (u & 0x80000000u) ? (u & 0x7FFFFFFFu) : ~u;
        float score = __uint_as_float(bits);
        int a = (int)(n % NA);
        int hw = (int)(n / NA);
        const float* rp = regs + ((size_t)b * (4 * NA) + 4 * a) * HWSZ + hw;
        float dx = rp[0 * HWSZ];
        float dy = rp[1 * HWSZ];
        float dh = rp[2 * HWSZ];
        float dw = rp[3 * HWSZ];
        const float* ap = anchors + ((size_t)b * NTOT + n) * 4;
        float ax1 = ap[0], ay1 = ap[1], ax2 = ap[2], ay2 = ap[3];
        float ahh = ay2 - ay1;
        float aww = ax2 - ax1;
        float cx = aww * 0.5f;
        float cy = ahh * 0.5f;
        float px = cx + dx * aww;
        float py = cy + dy * ahh;
        dh = fminf(dh, LOG_MAX_F);
        dw = fminf(dw, LOG_MAX_F);
        float ph = expf(dh) * ahh;
        float pw = expf(dw) * aww;
        float x1 = px - pw * 0.5f;
        float y1 = py - ph * 0.5f;
        float x2 = px + pw * 0.5f;
        float y2 = py + ph * 0.5f;
        float bwv = fminf(fmaxf(x2, 0.f), wimg) - fminf(fmaxf(x1, 0.f), wimg);
        float bhv = fminf(fmaxf(y2, 0.f), himg) - fminf(fmaxf(y1, 0.f), himg);
        unsigned int valid = (bwv >= 16.f && bhv >= 16.f) ? 1u : 0u;
        out_scores[o] = score;
        boxes_ws[o] = make_float4(x1, y1, x2, y2);
        valid_ws[o] = valid;
    }
}

// -------- Kernel 3: suppression bitmask matrix (rows x 64-col words) --------
__global__ __launch_bounds__(64) void k_supmat(const float4* __restrict__ boxes_ws,
                                               unsigned long long* __restrict__ sup) {
    int ct = blockIdx.x;    // col tile 0..31
    int rt = blockIdx.y;    // row tile 0..31
    int b  = blockIdx.z;
    int tid = threadIdx.x;
    __shared__ float4 colbox[64];
    int j0 = ct * 64;
    int jl = j0 + tid;
    colbox[tid] = (jl < KSEL) ? boxes_ws[(size_t)b * KSEL + jl]
                              : make_float4(0.f, 0.f, 0.f, 0.f);
    __syncthreads();
    int i = rt * 64 + tid;
    if (i >= KSEL) return;
    float4 bi = boxes_ws[(size_t)b * KSEL + i];
    float area_i = (bi.z - bi.x) * (bi.w - bi.y);
    unsigned long long word = 0ULL;
    #pragma unroll 8
    for (int jj = 0; jj < 64; ++jj) {
        int j = j0 + jj;
        float4 bj = colbox[jj];
        float area_j = (bj.z - bj.x) * (bj.w - bj.y);
        float ix1 = fmaxf(bi.x, bj.x);
        float iy1 = fmaxf(bi.y, bj.y);
        float ix2 = fminf(bi.z, bj.z);
        float iy2 = fminf(bi.w, bj.w);
        float iw = fmaxf(ix2 - ix1, 0.f);
        float ih = fmaxf(iy2 - iy1, 0.f);
        float inter = iw * ih;
        float uni = area_i + area_j - inter;
        float iou = inter / fmaxf(uni, 1e-6f);
        bool s = (j > i) && (j < KSEL) && (iou > 0.7f);
        if (s) word |= (1ULL << jj);
    }
    sup[((size_t)b * KSEL + i) * 32 + ct] = word;
}

// -------- Kernel 4: sequential greedy scan (1 wave / batch) + outputs --------
__global__ __launch_bounds__(64) void k_nms_scan(const unsigned long long* __restrict__ sup,
                                                 const unsigned int* __restrict__ valid_ws,
                                                 const float4* __restrict__ boxes_ws,
                                                 float* __restrict__ out_boxes,
                                                 float* __restrict__ out_keep) {
    int b = blockIdx.x;
    int lane = threadIdx.x;
    unsigned long long kw = 0ULL;
    if (lane < 32) {
        const unsigned int* v = valid_ws + (size_t)b * KSEL;
        int base = lane * 64;
        for (int bit = 0; bit < 64; ++bit) {
            int r = base + bit;
            if (r < KSEL && v[r]) kw |= (1ULL << bit);
        }
    }
    const unsigned long long* srow = sup + (size_t)b * KSEL * 32;
    for (int i = 0; i < KSEL; ++i) {
        int w = i >> 6;
        int bbit = i & 63;
        unsigned long long kwi = __shfl(kw, w, 64);
        if ((kwi >> bbit) & 1ULL) {
            if (lane < 32) kw &= ~srow[(size_t)i * 32 + lane];
        }
    }
    __shared__ unsigned long long kws[32];
    if (lane < 32) kws[lane] = kw;
    __syncthreads();
    for (int r = lane; r < KSEL; r += 64) {
        float kf = (float)((kws[r >> 6] >> (r & 63)) & 1ULL);
        size_t o = (size_t)b * KSEL + r;
        out_keep[o] = kf;
        float4 bx = boxes_ws[o];
        float* ob = out_boxes + o * 4;
        ob[0] = bx.x * kf;
        ob[1] = bx.y * kf;
        ob[2] = bx.z * kf;
        ob[3] = bx.w * kf;
    }
}

extern "C" void kernel_launch(void* const* d_in, const int* in_sizes, int n_in,
                              void* d_out, int out_size, void* d_ws, size_t ws_size,
                              hipStream_t stream) {
    const float* cls     = (const float*)d_in[0];
    const float* regs    = (const float*)d_in[1];
    const float* anchors = (const float*)d_in[2];
    const int*   img_h   = (const int*)d_in[3];
    const int*   img_w   = (const int*)d_in[4];

    float* out = (float*)d_out;
    float* out_boxes  = out;            // 8*2000*4 = 64000
    float* out_scores = out + 64000;    // 8*2000   = 16000
    float* out_keep   = out + 80000;    // 8*2000   = 16000

    char* ws = (char*)d_ws;
    unsigned long long* buf = (unsigned long long*)(ws + OFF_BUF);
    unsigned int* cnt       = (unsigned int*)(ws + OFF_CNT);
    float4* boxes_ws        = (float4*)(ws + OFF_BOX);
    unsigned int* valid_ws  = (unsigned int*)(ws + OFF_VALID);
    unsigned long long* sup = (unsigned long long*)(ws + OFF_SUP);

    k_select<<<NBATCH, 1024, 0, stream>>>(cls, buf, cnt);
    k_sort_decode<<<NBATCH, 1024, 0, stream>>>(buf, cnt, regs, anchors, img_h, img_w,
                                               out_scores, boxes_ws, valid_ws);
    k_supmat<<<dim3(32, 32, NBATCH), 64, 0, stream>>>(boxes_ws, sup);
    k_nms_scan<<<NBATCH, 64, 0, stream>>>(sup, valid_ws, boxes_ws, out_boxes, out_keep);
}